// Round 11
// baseline (120.801 us; speedup 1.0000x reference)
//
#include <hip/hip_runtime.h>
#include <float.h>

#define NB 1024
#define NT 200
#define ND 64
#define NH0 80
#define NH1 40
#define NROWS (NB*NT)
#define PSTRIDE 2048

typedef __attribute__((ext_vector_type(8))) short short8;
typedef __attribute__((ext_vector_type(4))) float f32x4;

__device__ __forceinline__ unsigned short f2bf_rne(float f) {
  union { float f; unsigned u; } v; v.f = f;
  unsigned u = v.u;
  unsigned r = (u + 0x7fffu + ((u >> 16) & 1u)) >> 16;
  return (unsigned short)r;
}
__device__ __forceinline__ float bf2f(unsigned short h) {
  union { unsigned u; float f; } v; v.u = ((unsigned)h) << 16;
  return v.f;
}

// ---------------- prep: (b, c-half) W_eff hi/lo + qc + mask flags; block 0 also W1^T ----------------
// grid = 2*NB
__global__ __launch_bounds__(256) void prep_kernel(
    const float* __restrict__ query, const float* __restrict__ W0,
    const float* __restrict__ b0, const float* __restrict__ W1,
    const unsigned* __restrict__ mask,
    unsigned short* __restrict__ weff_hi, unsigned short* __restrict__ weff_lo,
    float* __restrict__ qc_g,
    unsigned short* __restrict__ w1t_hi, unsigned short* __restrict__ w1t_lo,
    int* __restrict__ flagsP)
{
  __shared__ __align__(16) unsigned short sWhi[40*80];   // [c_local][d] stride 80
  __shared__ __align__(16) unsigned short sWlo[40*80];
  __shared__ float sq[64];
  __shared__ int sflag[2];
  int bid = blockIdx.x, b = bid >> 1, h = bid & 1, c0 = h*40;
  int tid = threadIdx.x;
  if (tid < 64) sq[tid] = query[b*64 + tid];
  if (tid < 2) sflag[tid] = 0;
  __syncthreads();
  // mask scan (h==0 blocks): 50 ints/b covers bytes [0,204800) under byte/int/float widths
  if (h == 0 && tid < 50) {
    unsigned v = mask[b*50 + tid];
    if (v > 1u) atomicOr(&sflag[0], 1);
    if (v != 0u && v != 1u && v != 0x3F800000u) atomicOr(&sflag[1], 1);
  }
  // W_eff[c][d] = (W0b - W0c)[d][c] + q[d]*W0d[d][c], c in [c0, c0+40)
  for (int idx = tid; idx < 2560; idx += 256) {
    int d = idx / 40, cl = idx - d*40, c = c0 + cl;
    float we = (W0[(64+d)*80 + c] - W0[(128+d)*80 + c]) + sq[d]*W0[(192+d)*80 + c];
    unsigned short hi = f2bf_rne(we);
    sWhi[cl*80 + d] = hi;
    sWlo[cl*80 + d] = f2bf_rne(we - bf2f(hi));
  }
  // qc: serial over d, coalesced across 40 threads (R4-proven pattern)
  if (tid < 40) {
    int c = c0 + tid;
    float s = b0[c];
    for (int d = 0; d < 64; ++d)
      s += sq[d] * (W0[d*80 + c] + W0[(128+d)*80 + c]);
    qc_g[b*80 + c] = s;
  }
  // W1^T padded [48][96] hi/lo (bid 0 only)
  if (bid == 0) {
    for (int idx = tid; idx < 48*96; idx += 256) {
      int c = idx / 96, k = idx - c*96;
      float w = (c < 40 && k < 80) ? W1[k*40 + c] : 0.f;
      unsigned short hi = f2bf_rne(w);
      w1t_hi[idx] = hi;
      w1t_lo[idx] = f2bf_rne(w - bf2f(hi));
    }
  }
  __syncthreads();
  // coalesced weff writeback (16B chunks)
  for (int i2 = tid; i2 < 320; i2 += 256) {
    int cl = i2 >> 3, dc = i2 & 7;
    uint4 vh = *reinterpret_cast<const uint4*>(&sWhi[cl*80 + dc*8]);
    uint4 vl = *reinterpret_cast<const uint4*>(&sWlo[cl*80 + dc*8]);
    *reinterpret_cast<uint4*>(&weff_hi[(size_t)b*5120 + (c0+cl)*64 + dc*8]) = vh;
    *reinterpret_cast<uint4*>(&weff_lo[(size_t)b*5120 + (c0+cl)*64 + dc*8]) = vl;
  }
  if (h == 0 && tid < 2) flagsP[b*2 + tid] = sflag[tid];
}

// ---------------- k1_main: (b, tile-half) h0 = k @ W_eff + qc via MFMA; prologue-free ----------------
// grid = 2*NB
template<bool STORE>
__global__ __launch_bounds__(256) void k1_main(
    const float* __restrict__ key,
    const unsigned short* __restrict__ weff_hi, const unsigned short* __restrict__ weff_lo,
    const float* __restrict__ qc_g,
    unsigned short* __restrict__ h0, float* __restrict__ p0)
{
  __shared__ float sred[160];
  int bid = blockIdx.x, b = bid >> 1, hh = bid & 1, tid = threadIdx.x;
  for (int i = tid; i < 160; i += 256) sred[i] = 0.f;
  int wv = tid >> 6, l = tid & 63, lm = l & 15, lg = l >> 4;

  const unsigned short* wh = weff_hi + (size_t)b*5120;
  const unsigned short* wl = weff_lo + (size_t)b*5120;
  short8 bfr[5][2][2];
#pragma unroll
  for (int n = 0; n < 5; ++n)
#pragma unroll
    for (int ks = 0; ks < 2; ++ks) {
      int off = (n*16 + lm)*64 + ks*32 + lg*8;
      bfr[n][ks][0] = *reinterpret_cast<const short8*>(wh + off);
      bfr[n][ks][1] = *reinterpret_cast<const short8*>(wl + off);
    }
  float qcv[5];
#pragma unroll
  for (int n = 0; n < 5; ++n) qcv[n] = qc_g[b*80 + n*16 + lm];
  __syncthreads();

  float accS[5] = {0,0,0,0,0}, accQ[5] = {0,0,0,0,0};
  const float* keyb = key + (size_t)b*NT*ND;

  int mt_lo = hh ? 7 : 0, mt_hi = hh ? 13 : 7;
  for (int mt = mt_lo + wv; mt < mt_hi; mt += 4) {
    int t0 = mt*16;
    int trow = t0 + lm;
    int tld = trow < NT ? trow : NT-1;
    const float* arow = keyb + (size_t)tld*ND;
    short8 ahi[2], alo[2];
#pragma unroll
    for (int ks = 0; ks < 2; ++ks) {
      float4 av0 = *reinterpret_cast<const float4*>(arow + ks*32 + lg*8);
      float4 av1 = *reinterpret_cast<const float4*>(arow + ks*32 + lg*8 + 4);
      float xs[8] = {av0.x, av0.y, av0.z, av0.w, av1.x, av1.y, av1.z, av1.w};
#pragma unroll
      for (int j = 0; j < 8; ++j) {
        unsigned short hb = f2bf_rne(xs[j]);
        ahi[ks][j] = (short)hb;
        alo[ks][j] = (short)f2bf_rne(xs[j] - bf2f(hb));
      }
    }
    f32x4 acc[5];
#pragma unroll
    for (int n = 0; n < 5; ++n) {
      acc[n][0] = qcv[n]; acc[n][1] = qcv[n]; acc[n][2] = qcv[n]; acc[n][3] = qcv[n];
    }
#pragma unroll
    for (int n = 0; n < 5; ++n)
#pragma unroll
      for (int ks = 0; ks < 2; ++ks) {
        acc[n] = __builtin_amdgcn_mfma_f32_16x16x32_bf16(ahi[ks], bfr[n][ks][0], acc[n], 0, 0, 0);
        acc[n] = __builtin_amdgcn_mfma_f32_16x16x32_bf16(ahi[ks], bfr[n][ks][1], acc[n], 0, 0, 0);
        acc[n] = __builtin_amdgcn_mfma_f32_16x16x32_bf16(alo[ks], bfr[n][ks][0], acc[n], 0, 0, 0);
      }
    // C/D layout: col = lane&15, row = (lane>>4)*4 + reg
#pragma unroll
    for (int n = 0; n < 5; ++n)
#pragma unroll
      for (int r = 0; r < 4; ++r) {
        int row = t0 + lg*4 + r;
        if (row < NT) {
          float h = acc[n][r];
          if (STORE) h0[((size_t)b*NT + row)*NH0 + n*16 + lm] = f2bf_rne(h);
          accS[n] += h; accQ[n] += h*h;
        }
      }
  }
#pragma unroll
  for (int n = 0; n < 5; ++n) {
    accS[n] += __shfl_xor(accS[n], 16); accS[n] += __shfl_xor(accS[n], 32);
    accQ[n] += __shfl_xor(accQ[n], 16); accQ[n] += __shfl_xor(accQ[n], 32);
  }
  if (lg == 0) {
#pragma unroll
    for (int n = 0; n < 5; ++n) {
      atomicAdd(&sred[n*16 + lm], accS[n]);
      atomicAdd(&sred[80 + n*16 + lm], accQ[n]);
    }
  }
  __syncthreads();
  if (tid < 160) p0[(size_t)tid * PSTRIDE + bid] = sred[tid];
}

// ---------------- k2_main: h1 = dice0(h0)@W1 + b1 via MFMA; prologue-free ----------------
__global__ __launch_bounds__(256) void k2_main(
    const unsigned short* __restrict__ h0,
    const unsigned short* __restrict__ w1t_hi, const unsigned short* __restrict__ w1t_lo,
    const float* __restrict__ b1, const float* __restrict__ alpha0,
    const float* __restrict__ stats,
    unsigned short* __restrict__ h1, float* __restrict__ p1)
{
  __shared__ float sm0[96], si0[96], sa0[96];
  __shared__ float sb1[48];
  __shared__ float sred[80];
  int tid = threadIdx.x;
  if (tid < 96) {
    sm0[tid] = (tid < 80) ? stats[tid] : 0.f;
    si0[tid] = (tid < 80) ? stats[80 + tid] : 0.f;
    sa0[tid] = (tid < 80) ? alpha0[tid] : 0.f;
  }
  if (tid >= 96 && tid < 144) sb1[tid-96] = (tid-96 < 40) ? b1[tid-96] : 0.f;
  if (tid >= 144 && tid < 224) sred[tid-144] = 0.f;
  __syncthreads();

  int wv = tid >> 6, l = tid & 63, lm = l & 15, lg = l >> 4;

  short8 bfr[3][3][2];
#pragma unroll
  for (int n = 0; n < 3; ++n)
#pragma unroll
    for (int ks = 0; ks < 3; ++ks) {
      int off = (n*16 + lm)*96 + ks*32 + lg*8;
      bfr[n][ks][0] = *reinterpret_cast<const short8*>(w1t_hi + off);
      bfr[n][ks][1] = *reinterpret_cast<const short8*>(w1t_lo + off);
    }
  float dm[3][8], di[3][8], da[3][8];
#pragma unroll
  for (int ks = 0; ks < 3; ++ks) {
    int k0 = ks*32 + lg*8;
#pragma unroll
    for (int j = 0; j < 8; ++j) {
      dm[ks][j] = sm0[k0+j]; di[ks][j] = si0[k0+j]; da[ks][j] = sa0[k0+j];
    }
  }

  float accS[3] = {0,0,0}, accQ[3] = {0,0,0};
  size_t row0 = (size_t)blockIdx.x*128 + wv*32;

  for (int mt = 0; mt < 2; ++mt) {
    size_t row = row0 + mt*16 + lm;
    const unsigned short* arow = h0 + row*NH0;
    short8 ya[3];
#pragma unroll
    for (int ks = 0; ks < 3; ++ks) {
      int el0 = ks*32 + lg*8;
      int elc = (el0 < 80) ? el0 : 0;
      uint4 xv = *reinterpret_cast<const uint4*>(arow + elc);
      unsigned uu[4] = {xv.x, xv.y, xv.z, xv.w};
#pragma unroll
      for (int j = 0; j < 8; ++j) {
        unsigned short hx = (j & 1) ? (unsigned short)(uu[j>>1] >> 16)
                                    : (unsigned short)(uu[j>>1] & 0xffffu);
        float x = bf2f(hx);
        float xn = (x - dm[ks][j]) * di[ks][j];
        float pp = 1.f / (1.f + __expf(-xn));
        float y = x * (da[ks][j] + pp*(1.f - da[ks][j]));
        ya[ks][j] = (short)f2bf_rne(y);
      }
    }
    f32x4 acc[3];
#pragma unroll
    for (int n = 0; n < 3; ++n) {
      float bv = sb1[n*16 + lm];
      acc[n][0] = bv; acc[n][1] = bv; acc[n][2] = bv; acc[n][3] = bv;
    }
#pragma unroll
    for (int n = 0; n < 3; ++n)
#pragma unroll
      for (int ks = 0; ks < 3; ++ks) {
        acc[n] = __builtin_amdgcn_mfma_f32_16x16x32_bf16(ya[ks], bfr[n][ks][0], acc[n], 0, 0, 0);
        acc[n] = __builtin_amdgcn_mfma_f32_16x16x32_bf16(ya[ks], bfr[n][ks][1], acc[n], 0, 0, 0);
      }
#pragma unroll
    for (int n = 0; n < 3; ++n) {
      int c = n*16 + lm;
#pragma unroll
      for (int r = 0; r < 4; ++r) {
        float h = acc[n][r];
        if (c < 40) {
          size_t orow = row0 + mt*16 + lg*4 + r;
          h1[orow*NH1 + c] = f2bf_rne(h);
          accS[n] += h; accQ[n] += h*h;
        }
      }
    }
  }
#pragma unroll
  for (int n = 0; n < 3; ++n) {
    accS[n] += __shfl_xor(accS[n], 16); accS[n] += __shfl_xor(accS[n], 32);
    accQ[n] += __shfl_xor(accQ[n], 16); accQ[n] += __shfl_xor(accQ[n], 32);
  }
  if (lg == 0) {
#pragma unroll
    for (int n = 0; n < 3; ++n) {
      int c = n*16 + lm;
      if (c < 40) { atomicAdd(&sred[c], accS[n]); atomicAdd(&sred[40 + c], accQ[n]); }
    }
  }
  __syncthreads();
  if (tid < 80) p1[(size_t)tid * PSTRIDE + blockIdx.x] = sred[tid];
}

// ---------------- partial -> mean/inv reduction (+ optional mask-flag fold) ----------------
__global__ __launch_bounds__(256) void reduce_stats_kernel(
    const float* __restrict__ p, int stride, int nblk, int nch,
    float* __restrict__ mean_out, float* __restrict__ inv_out,
    const int* __restrict__ flagsP, int* __restrict__ flags_out, int nflag)
{
  int c = blockIdx.x, tid = threadIdx.x;
  float s = 0.f, q = 0.f;
  for (int j = tid; j < nblk; j += 256) {
    s += p[(size_t)c*stride + j];
    q += p[(size_t)(nch + c)*stride + j];
  }
#pragma unroll
  for (int off = 32; off > 0; off >>= 1) { s += __shfl_xor(s, off); q += __shfl_xor(q, off); }
  __shared__ float ss[4], sq[4];
  __shared__ int sfo[2];
  if ((tid & 63) == 0) { ss[tid >> 6] = s; sq[tid >> 6] = q; }
  if (tid < 2) sfo[tid] = 0;
  __syncthreads();
  if (tid == 0) {
    float S = ss[0]+ss[1]+ss[2]+ss[3], Q = sq[0]+sq[1]+sq[2]+sq[3];
    float invN = 1.f / (float)NROWS;
    float mean = S * invN;
    float var  = Q * invN - mean*mean;
    mean_out[c] = mean;
    inv_out[c]  = rsqrtf(var + 1e-9f);
  }
  if (flagsP != nullptr && c == 0) {
    int f0 = 0, f1 = 0;
    for (int i = tid; i < nflag; i += 256) { f0 |= flagsP[2*i]; f1 |= flagsP[2*i + 1]; }
    if (f0) atomicOr(&sfo[0], 1);
    if (f1) atomicOr(&sfo[1], 1);
    __syncthreads();
    if (tid < 2) flags_out[tid] = sfo[tid];
  }
}

// ---------------- k3: (b, dim-half) dice1, scores, softmax, attn@key ----------------
// grid = 2*NB; each block stages key[:, dh*32 .. dh*32+32) fp32 (25.6KB) and owns 32 output dims.
__device__ __forceinline__ bool read_mask(const void* mask, int mode, size_t mi) {
  if (mode == 0) return ((const int*)mask)[mi] != 0;
  if (mode == 1) return ((const unsigned char*)mask)[mi] != 0;
  return ((const float*)mask)[mi] != 0.f;
}

__global__ __launch_bounds__(256) void k3_kernel(
    const unsigned short* __restrict__ h1, const float* __restrict__ Wout,
    const float* __restrict__ bout, const float* __restrict__ alpha1,
    const void* __restrict__ mask, const float* __restrict__ key,
    const float* __restrict__ stats, const int* __restrict__ flags,
    float* __restrict__ out)
{
  __shared__ float sk[NT*32];                 // 25,600 B key half-block
  __shared__ float sWo[40], sm1[40], si1[40], sa1[40];
  __shared__ float sp[256], sredm[4], ssum[4], sout[256];
  int bid = blockIdx.x, b = bid >> 1, dh = bid & 1, tid = threadIdx.x;

  // bulk-parallel stage: key[b][t][dh*32 + j] (8 float4 per row)
  const float4* kb4 = (const float4*)key;
  float4* sk4 = (float4*)sk;
  for (int i = tid; i < NT*8; i += 256) {
    int t = i >> 3, j = i & 7;
    sk4[i] = kb4[(size_t)b*(NT*ND/4) + t*(ND/4) + dh*8 + j];
  }

  if (tid < 40) {
    sWo[tid] = Wout[tid];
    sm1[tid] = stats[160 + tid]; si1[tid] = stats[200 + tid]; sa1[tid] = alpha1[tid];
  }
  __syncthreads();
  int mode = (flags[0] == 0) ? 0 : ((flags[1] == 0) ? 2 : 1);
  float sc = -FLT_MAX;
  if (tid < NT) {
    const uint4* xr = (const uint4*)(h1 + ((size_t)b*NT + tid)*NH1);
    float s = bout[0];
#pragma unroll
    for (int cq = 0; cq < 5; ++cq) {
      uint4 xv = xr[cq];
      unsigned uu[4] = {xv.x, xv.y, xv.z, xv.w};
#pragma unroll
      for (int u = 0; u < 8; ++u) {
        int c = cq*8 + u;
        unsigned short hx = (u & 1) ? (unsigned short)(uu[u>>1] >> 16)
                                    : (unsigned short)(uu[u>>1] & 0xffffu);
        float x = bf2f(hx);
        float xn = (x - sm1[c]) * si1[c];
        float p = 1.f / (1.f + __expf(-xn));
        float y = x * (sa1[c] + p*(1.f - sa1[c]));
        s = fmaf(y, sWo[c], s);
      }
    }
    if (read_mask(mask, mode, (size_t)b*NT + tid)) sc = s;
  }
  // softmax (4-wave reduce)
  float m = sc;
#pragma unroll
  for (int off = 32; off > 0; off >>= 1) m = fmaxf(m, __shfl_xor(m, off));
  if ((tid & 63) == 0) sredm[tid >> 6] = m;
  __syncthreads();
  float mm = fmaxf(fmaxf(sredm[0], sredm[1]), fmaxf(sredm[2], sredm[3]));
  float e = (sc > -FLT_MAX) ? __expf(sc - mm) : 0.f;
  float sv = e;
#pragma unroll
  for (int off = 32; off > 0; off >>= 1) sv += __shfl_xor(sv, off);
  if ((tid & 63) == 0) ssum[tid >> 6] = sv;
  __syncthreads();
  float inv = 1.f / (ssum[0] + ssum[1] + ssum[2] + ssum[3]);
  sp[tid] = e * inv;
  __syncthreads();
  // PV over this block's 32 dims: 8 row-groups x 32 dims, 4-way split accumulators
  int rg = tid >> 5, dim = tid & 31;
  float a0 = 0.f, a1 = 0.f, a2 = 0.f, a3 = 0.f;
  int t = rg;
  for (; t + 24 < NT; t += 32) {
    a0 = fmaf(sp[t],    sk[t*32 + dim],      a0);
    a1 = fmaf(sp[t+8],  sk[(t+8)*32 + dim],  a1);
    a2 = fmaf(sp[t+16], sk[(t+16)*32 + dim], a2);
    a3 = fmaf(sp[t+24], sk[(t+24)*32 + dim], a3);
  }
  for (; t < NT; t += 8) a0 = fmaf(sp[t], sk[t*32 + dim], a0);
  sout[tid] = (a0 + a1) + (a2 + a3);
  __syncthreads();
  if (tid < 32) {
    float v = 0.f;
#pragma unroll
    for (int g = 0; g < 8; ++g) v += sout[g*32 + tid];
    out[b*64 + dh*32 + tid] = v;
  }
}

// ================= fallback kernels (small ws) =================

__global__ void detect_mask_kernel(const unsigned* __restrict__ m, int* __restrict__ flags) {
  int i = blockIdx.x * 256 + threadIdx.x;
  if (i < NROWS / 4) {
    unsigned v = m[i];
    if (v > 1u) atomicOr(&flags[0], 1);
    if (v != 0u && v != 1u && v != 0x3F800000u) atomicOr(&flags[1], 1);
  }
}

__device__ __forceinline__ void softmax_and_out(
    int b, int tid, float sc, float* sp, float* sredm, float* ssum, float* sout,
    const float* __restrict__ key, float* __restrict__ out)
{
  float m = sc;
#pragma unroll
  for (int off = 32; off > 0; off >>= 1) m = fmaxf(m, __shfl_xor(m, off));
  if ((tid & 63) == 0) sredm[tid >> 6] = m;
  __syncthreads();
  float mm = fmaxf(fmaxf(sredm[0], sredm[1]), fmaxf(sredm[2], sredm[3]));
  float e = (sc > -FLT_MAX) ? __expf(sc - mm) : 0.f;
  float sv = e;
#pragma unroll
  for (int off = 32; off > 0; off >>= 1) sv += __shfl_xor(sv, off);
  if ((tid & 63) == 0) ssum[tid >> 6] = sv;
  __syncthreads();
  float inv = 1.f / (ssum[0] + ssum[1] + ssum[2] + ssum[3]);
  sp[tid] = e * inv;
  __syncthreads();
  int wid = tid >> 6, lane = tid & 63;
  const float* keyb = key + (size_t)b*NT*ND;
  float acc = 0.f;
  for (int t = wid; t < NT; t += 4) acc = fmaf(sp[t], keyb[t*ND + lane], acc);
  sout[tid] = acc;
  __syncthreads();
  if (tid < 64) out[b*64 + tid] = sout[tid] + sout[64+tid] + sout[128+tid] + sout[192+tid];
}

__global__ __launch_bounds__(256) void k1_old(
    const float* __restrict__ query, const float* __restrict__ key,
    const float* __restrict__ W0, const float* __restrict__ b0,
    float* __restrict__ p0)
{
  __shared__ __align__(16) unsigned short sWhi[80*72];
  __shared__ __align__(16) unsigned short sWlo[80*72];
  __shared__ float sq[64];
  __shared__ float sqc[80];
  __shared__ float sred[160];
  int b = blockIdx.x, tid = threadIdx.x;

  if (tid < 64) sq[tid] = query[b*64 + tid];
  for (int i = tid; i < 160; i += 256) sred[i] = 0.f;
  __syncthreads();
  for (int idx = tid; idx < 64*80; idx += 256) {
    int d = idx / 80, c = idx - d*80;
    float we = (W0[(64+d)*80 + c] - W0[(128+d)*80 + c]) + sq[d]*W0[(192+d)*80 + c];
    unsigned short hi = f2bf_rne(we);
    sWhi[c*72 + d] = hi;
    sWlo[c*72 + d] = f2bf_rne(we - bf2f(hi));
  }
  if (tid < 80) {
    float s = b0[tid];
    for (int d = 0; d < 64; ++d)
      s += sq[d] * (W0[d*80 + tid] + W0[(128+d)*80 + tid]);
    sqc[tid] = s;
  }
  __syncthreads();

  int wv = tid >> 6, l = tid & 63;
  int lm = l & 15, lg = l >> 4;
  short8 bfr[5][2][2];
#pragma unroll
  for (int n = 0; n < 5; ++n)
#pragma unroll
    for (int ks = 0; ks < 2; ++ks) {
      int off = (n*16 + lm)*72 + ks*32 + lg*8;
      bfr[n][ks][0] = *reinterpret_cast<const short8*>(&sWhi[off]);
      bfr[n][ks][1] = *reinterpret_cast<const short8*>(&sWlo[off]);
    }
  float accS[5] = {0,0,0,0,0}, accQ[5] = {0,0,0,0,0};
  const float* keyb = key + (size_t)b*NT*ND;

  for (int mt = wv; mt < 13; mt += 4) {
    int t0 = mt*16;
    int trow = t0 + lm;
    int tld = trow < NT ? trow : NT-1;
    const float* arow = keyb + (size_t)tld*ND;
    short8 ahi[2], alo[2];
#pragma unroll
    for (int ks = 0; ks < 2; ++ks) {
      float4 av0 = *reinterpret_cast<const float4*>(arow + ks*32 + lg*8);
      float4 av1 = *reinterpret_cast<const float4*>(arow + ks*32 + lg*8 + 4);
      float xs[8] = {av0.x, av0.y, av0.z, av0.w, av1.x, av1.y, av1.z, av1.w};
#pragma unroll
      for (int j = 0; j < 8; ++j) {
        unsigned short hb = f2bf_rne(xs[j]);
        ahi[ks][j] = (short)hb;
        alo[ks][j] = (short)f2bf_rne(xs[j] - bf2f(hb));
      }
    }
    f32x4 acc[5];
#pragma unroll
    for (int n = 0; n < 5; ++n) {
      float qcv = sqc[n*16 + lm];
      acc[n][0] = qcv; acc[n][1] = qcv; acc[n][2] = qcv; acc[n][3] = qcv;
    }
#pragma unroll
    for (int n = 0; n < 5; ++n)
#pragma unroll
      for (int ks = 0; ks < 2; ++ks) {
        acc[n] = __builtin_amdgcn_mfma_f32_16x16x32_bf16(ahi[ks], bfr[n][ks][0], acc[n], 0, 0, 0);
        acc[n] = __builtin_amdgcn_mfma_f32_16x16x32_bf16(ahi[ks], bfr[n][ks][1], acc[n], 0, 0, 0);
        acc[n] = __builtin_amdgcn_mfma_f32_16x16x32_bf16(alo[ks], bfr[n][ks][0], acc[n], 0, 0, 0);
      }
#pragma unroll
    for (int n = 0; n < 5; ++n)
#pragma unroll
      for (int r = 0; r < 4; ++r) {
        int row = t0 + lg*4 + r;
        if (row < NT) { float h = acc[n][r]; accS[n] += h; accQ[n] += h*h; }
      }
  }
#pragma unroll
  for (int n = 0; n < 5; ++n) {
    accS[n] += __shfl_xor(accS[n], 16); accS[n] += __shfl_xor(accS[n], 32);
    accQ[n] += __shfl_xor(accQ[n], 16); accQ[n] += __shfl_xor(accQ[n], 32);
  }
  if (lg == 0) {
#pragma unroll
    for (int n = 0; n < 5; ++n) {
      atomicAdd(&sred[n*16 + lm], accS[n]);
      atomicAdd(&sred[80 + n*16 + lm], accQ[n]);
    }
  }
  __syncthreads();
  if (tid < 160) p0[(size_t)tid * PSTRIDE + b] = sred[tid];
}

template<bool STOREH1>
__global__ __launch_bounds__(256) void k2_rec_kernel(
    const float* __restrict__ query, const float* __restrict__ key,
    const float* __restrict__ W0, const float* __restrict__ b0,
    const float* __restrict__ W1, const float* __restrict__ b1,
    const float* __restrict__ alpha0,
    unsigned short* __restrict__ h1, const float* __restrict__ stats,
    float* __restrict__ p1)
{
  __shared__ float sWb[64*80], sWd[64*80], sW1[80*40];
  __shared__ float sq[64], sqc[80], sb1[40];
  __shared__ float sm0[80], si0[80], sa0[80];
  __shared__ float swp[4*80];
  int b = blockIdx.x, tid = threadIdx.x;
  for (int idx = tid; idx < 64*80; idx += 256) {
    int d = idx / 80, c = idx - d*80;
    sWb[idx] = W0[(64+d)*80 + c] - W0[(128+d)*80 + c];
    sWd[idx] = W0[(192+d)*80 + c];
  }
  for (int idx = tid; idx < 3200; idx += 256) sW1[idx] = W1[idx];
  if (tid < 64) sq[tid] = query[b*64 + tid];
  if (tid < 40) sb1[tid] = b1[tid];
  if (tid >= 64 && tid < 144) {
    int c = tid - 64;
    sm0[c] = stats[c]; si0[c] = stats[80 + c]; sa0[c] = alpha0[c];
  }
  __syncthreads();
  if (tid < 80) {
    float s = b0[tid];
    for (int d = 0; d < 64; ++d)
      s += sq[d] * (W0[d*80 + tid] + W0[(128+d)*80 + tid]);
    sqc[tid] = s;
  }
  __syncthreads();
  int t = tid;
  bool active = t < NT;
  float h0r[80];
#pragma unroll
  for (int c = 0; c < 80; ++c) h0r[c] = sqc[c];
  const float* krow = key + ((size_t)b*NT + (active ? t : 0))*ND;
  for (int dq = 0; dq < 16; ++dq) {
    float4 kv = ((const float4*)krow)[dq];
#pragma unroll
    for (int u = 0; u < 4; ++u) {
      int d = dq*4 + u;
      float kd = (&kv.x)[u];
      float qk = sq[d] * kd;
#pragma unroll
      for (int c = 0; c < 80; ++c)
        h0r[c] = fmaf(kd, sWb[d*80 + c], fmaf(qk, sWd[d*80 + c], h0r[c]));
    }
  }
  float h1r[40];
#pragma unroll
  for (int c = 0; c < 40; ++c) h1r[c] = sb1[c];
#pragma unroll
  for (int d = 0; d < 80; ++d) {
    float x = h0r[d];
    float xn = (x - sm0[d]) * si0[d];
    float p = 1.f / (1.f + __expf(-xn));
    float y = x * (sa0[d] + p*(1.f - sa0[d]));
#pragma unroll
    for (int c = 0; c < 40; ++c) h1r[c] = fmaf(y, sW1[d*40 + c], h1r[c]);
  }
  if (STOREH1 && active) {
    uint4* orow = (uint4*)(h1 + ((size_t)b*NT + t)*NH1);
#pragma unroll
    for (int cq = 0; cq < 5; ++cq) {
      uint4 o;
      o.x = (unsigned)f2bf_rne(h1r[cq*8+0]) | ((unsigned)f2bf_rne(h1r[cq*8+1]) << 16);
      o.y = (unsigned)f2bf_rne(h1r[cq*8+2]) | ((unsigned)f2bf_rne(h1r[cq*8+3]) << 16);
      o.z = (unsigned)f2bf_rne(h1r[cq*8+4]) | ((unsigned)f2bf_rne(h1r[cq*8+5]) << 16);
      o.w = (unsigned)f2bf_rne(h1r[cq*8+6]) | ((unsigned)f2bf_rne(h1r[cq*8+7]) << 16);
      orow[cq] = o;
    }
  }
  int lane = tid & 63, wid = tid >> 6;
#pragma unroll
  for (int c = 0; c < 40; ++c) {
    float v = active ? h1r[c] : 0.f;
    float s = v, q = v*v;
#pragma unroll
    for (int off = 32; off > 0; off >>= 1) { s += __shfl_xor(s, off); q += __shfl_xor(q, off); }
    if (lane == 0) { swp[wid*80 + c] = s; swp[wid*80 + 40 + c] = q; }
  }
  __syncthreads();
  if (tid < 80) {
    float v = swp[tid] + swp[80+tid] + swp[160+tid] + swp[240+tid];
    p1[(size_t)tid * PSTRIDE + b] = v;
  }
}

__global__ __launch_bounds__(256) void k3_rec_kernel(
    const float* __restrict__ query, const float* __restrict__ key,
    const float* __restrict__ W0, const float* __restrict__ b0,
    const float* __restrict__ W1, const float* __restrict__ b1,
    const float* __restrict__ alpha0, const float* __restrict__ Wout,
    const float* __restrict__ bout, const float* __restrict__ alpha1,
    const void* __restrict__ mask,
    const float* __restrict__ stats, const int* __restrict__ flags,
    float* __restrict__ out)
{
  __shared__ float sWb[64*80], sWd[64*80], sW1[80*40];
  __shared__ float sq[64], sqc[80], sb1[40];
  __shared__ float sm0[80], si0[80], sa0[80];
  __shared__ float sWo[40], sm1[40], si1[40], sa1[40];
  __shared__ float sp[256], sredm[4], ssum[4], sout[256];
  int b = blockIdx.x, tid = threadIdx.x;
  for (int idx = tid; idx < 64*80; idx += 256) {
    int d = idx / 80, c = idx - d*80;
    sWb[idx] = W0[(64+d)*80 + c] - W0[(128+d)*80 + c];
    sWd[idx] = W0[(192+d)*80 + c];
  }
  for (int idx = tid; idx < 3200; idx += 256) sW1[idx] = W1[idx];
  if (tid < 64) sq[tid] = query[b*64 + tid];
  if (tid < 40) sb1[tid] = b1[tid];
  if (tid >= 64 && tid < 144) {
    int c = tid - 64;
    sm0[c] = stats[c]; si0[c] = stats[80 + c]; sa0[c] = alpha0[c];
  }
  if (tid >= 144 && tid < 184) {
    int c = tid - 144;
    sm1[c] = stats[160 + c]; si1[c] = stats[200 + c]; sa1[c] = alpha1[c];
    sWo[c] = Wout[c];
  }
  __syncthreads();
  if (tid < 80) {
    float s = b0[tid];
    for (int d = 0; d < 64; ++d)
      s += sq[d] * (W0[d*80 + tid] + W0[(128+d)*80 + tid]);
    sqc[tid] = s;
  }
  __syncthreads();
  int t = tid;
  bool active = t < NT;
  int mode = (flags[0] == 0) ? 0 : ((flags[1] == 0) ? 2 : 1);
  float sc = -FLT_MAX;
  {
    float h0r[80];
#pragma unroll
    for (int c = 0; c < 80; ++c) h0r[c] = sqc[c];
    const float* krow = key + ((size_t)b*NT + (active ? t : 0))*ND;
    for (int dq = 0; dq < 16; ++dq) {
      float4 kv = ((const float4*)krow)[dq];
#pragma unroll
      for (int u = 0; u < 4; ++u) {
        int d = dq*4 + u;
        float kd = (&kv.x)[u];
        float qk = sq[d] * kd;
#pragma unroll
        for (int c = 0; c < 80; ++c)
          h0r[c] = fmaf(kd, sWb[d*80 + c], fmaf(qk, sWd[d*80 + c], h0r[c]));
      }
    }
    float h1r[40];
#pragma unroll
    for (int c = 0; c < 40; ++c) h1r[c] = sb1[c];
#pragma unroll
    for (int d = 0; d < 80; ++d) {
      float x = h0r[d];
      float xn = (x - sm0[d]) * si0[d];
      float p = 1.f / (1.f + __expf(-xn));
      float y = x * (sa0[d] + p*(1.f - sa0[d]));
#pragma unroll
      for (int c = 0; c < 40; ++c) h1r[c] = fmaf(y, sW1[d*40 + c], h1r[c]);
    }
    float s = bout[0];
#pragma unroll
    for (int c = 0; c < 40; ++c) {
      float x = h1r[c];
      float xn = (x - sm1[c]) * si1[c];
      float p = 1.f / (1.f + __expf(-xn));
      float y = x * (sa1[c] + p*(1.f - sa1[c]));
      s = fmaf(y, sWo[c], s);
    }
    if (active && read_mask(mask, mode, (size_t)b*NT + t)) sc = s;
  }
  softmax_and_out(b, tid, sc, sp, sredm, ssum, sout, key, out);
}

// ================= launch =================

extern "C" void kernel_launch(void* const* d_in, const int* in_sizes, int n_in,
                              void* d_out, int out_size, void* d_ws, size_t ws_size,
                              hipStream_t stream) {
  const float* query  = (const float*)d_in[0];
  const float* key    = (const float*)d_in[1];
  const void*  mask   = d_in[2];
  const float* W0     = (const float*)d_in[3];
  const float* b0     = (const float*)d_in[4];
  const float* alpha0 = (const float*)d_in[5];
  const float* W1     = (const float*)d_in[6];
  const float* b1     = (const float*)d_in[7];
  const float* alpha1 = (const float*)d_in[8];
  const float* Wout   = (const float*)d_in[9];
  const float* bout   = (const float*)d_in[10];
  float* out = (float*)d_out;

  char* wsb = (char*)d_ws;
  float* stats = (float*)wsb;              // 960 B
  int* flags = (int*)(wsb + 960);          // 2 ints

  const size_t off_p0     = 1024;
  const size_t off_p1     = 1311744;
  const size_t off_flagsP = 1967104;
  const size_t off_qc     = 1975296;
  const size_t off_w1h    = 2302976;
  const size_t off_w1l    = 2312192;
  const size_t off_whi    = 2321408;
  const size_t off_wlo    = 12807168;
  const size_t off_h0     = 23292928;
  const size_t off_h1     = 56060928;
  const size_t END_FULL   = 72444928;
  const size_t END_MID    = off_h0 + 16384000;

  float* p0 = (float*)(wsb + off_p0);
  float* p1 = (float*)(wsb + off_p1);
  int* flagsP = (int*)(wsb + off_flagsP);
  float* qc_g = (float*)(wsb + off_qc);
  unsigned short* w1t_hi = (unsigned short*)(wsb + off_w1h);
  unsigned short* w1t_lo = (unsigned short*)(wsb + off_w1l);
  unsigned short* weff_hi = (unsigned short*)(wsb + off_whi);
  unsigned short* weff_lo = (unsigned short*)(wsb + off_wlo);

  if (ws_size >= END_FULL) {
    unsigned short* h0 = (unsigned short*)(wsb + off_h0);
    unsigned short* h1 = (unsigned short*)(wsb + off_h1);
    prep_kernel<<<2*NB, 256, 0, stream>>>(query, W0, b0, W1, (const unsigned*)mask,
                                          weff_hi, weff_lo, qc_g, w1t_hi, w1t_lo, flagsP);
    k1_main<true><<<2*NB, 256, 0, stream>>>(key, weff_hi, weff_lo, qc_g, h0, p0);
    reduce_stats_kernel<<<80, 256, 0, stream>>>(p0, PSTRIDE, 2*NB, 80, stats, stats + 80,
                                                flagsP, flags, NB);
    k2_main<<<NROWS/128, 256, 0, stream>>>(h0, w1t_hi, w1t_lo, b1, alpha0, stats, h1, p1);
    reduce_stats_kernel<<<40, 256, 0, stream>>>(p1, PSTRIDE, NROWS/128, 40, stats + 160, stats + 200,
                                                nullptr, nullptr, 0);
    k3_kernel<<<2*NB, 256, 0, stream>>>(h1, Wout, bout, alpha1, mask, key, stats, flags, out);
  } else if (ws_size >= END_MID) {
    unsigned short* h1 = (unsigned short*)(wsb + off_h0);
    prep_kernel<<<2*NB, 256, 0, stream>>>(query, W0, b0, W1, (const unsigned*)mask,
                                          weff_hi, weff_lo, qc_g, w1t_hi, w1t_lo, flagsP);
    k1_main<false><<<2*NB, 256, 0, stream>>>(key, weff_hi, weff_lo, qc_g, nullptr, p0);
    reduce_stats_kernel<<<80, 256, 0, stream>>>(p0, PSTRIDE, 2*NB, 80, stats, stats + 80,
                                                flagsP, flags, NB);
    k2_rec_kernel<true><<<NB, 256, 0, stream>>>(query, key, W0, b0, W1, b1, alpha0, h1, stats, p1);
    reduce_stats_kernel<<<40, 256, 0, stream>>>(p1, PSTRIDE, NB, 40, stats + 160, stats + 200,
                                                nullptr, nullptr, 0);
    k3_kernel<<<2*NB, 256, 0, stream>>>(h1, Wout, bout, alpha1, mask, key, stats, flags, out);
  } else {
    hipMemsetAsync(d_ws, 0, 1024, stream);
    detect_mask_kernel<<<200, 256, 0, stream>>>((const unsigned*)mask, flags);
    k1_old<<<NB, 256, 0, stream>>>(query, key, W0, b0, p0);
    reduce_stats_kernel<<<80, 256, 0, stream>>>(p0, PSTRIDE, NB, 80, stats, stats + 80,
                                                nullptr, nullptr, 0);
    k2_rec_kernel<false><<<NB, 256, 0, stream>>>(query, key, W0, b0, W1, b1, alpha0, nullptr, stats, p1);
    reduce_stats_kernel<<<40, 256, 0, stream>>>(p1, PSTRIDE, NB, 40, stats + 160, stats + 200,
                                                nullptr, nullptr, 0);
    k3_rec_kernel<<<NB, 256, 0, stream>>>(query, key, W0, b0, W1, b1, alpha0, Wout, bout, alpha1,
                                          mask, stats, flags, out);
  }
}

// Round 12
// 100.530 us; speedup vs baseline: 1.2016x; 1.2016x over previous
//
#include <hip/hip_runtime.h>
#include <float.h>

#define NB 1024
#define NT 200
#define ND 64
#define NH0 80
#define NH1 40
#define NROWS (NB*NT)
#define PSTRIDE 2048

typedef __attribute__((ext_vector_type(8))) short short8;
typedef __attribute__((ext_vector_type(4))) float f32x4;

__device__ __forceinline__ unsigned short f2bf_rne(float f) {
  union { float f; unsigned u; } v; v.f = f;
  unsigned u = v.u;
  unsigned r = (u + 0x7fffu + ((u >> 16) & 1u)) >> 16;
  return (unsigned short)r;
}
__device__ __forceinline__ float bf2f(unsigned short h) {
  union { unsigned u; float f; } v; v.u = ((unsigned)h) << 16;
  return v.f;
}

// ---------------- prep: per-b W_eff hi/lo + qc + mask flags; b==0 also W1^T hi/lo ----------------
__global__ __launch_bounds__(256) void prep_kernel(
    const float* __restrict__ query, const float* __restrict__ W0,
    const float* __restrict__ b0, const float* __restrict__ W1,
    const unsigned* __restrict__ mask,
    unsigned short* __restrict__ weff_hi, unsigned short* __restrict__ weff_lo,
    float* __restrict__ qc_g,
    unsigned short* __restrict__ w1t_hi, unsigned short* __restrict__ w1t_lo,
    int* __restrict__ flagsP)
{
  __shared__ __align__(16) unsigned short sWhi[80*80];   // [c][d] stride 80
  __shared__ __align__(16) unsigned short sWlo[80*80];
  __shared__ float sq[64];
  __shared__ int sflag[2];
  int b = blockIdx.x, tid = threadIdx.x;
  if (tid < 64) sq[tid] = query[b*64 + tid];
  if (tid < 2) sflag[tid] = 0;
  __syncthreads();
  // mask scan: 50 ints/b covers bytes [0,204800) under byte/int/float widths
  if (tid < 50) {
    unsigned v = mask[b*50 + tid];
    if (v > 1u) atomicOr(&sflag[0], 1);
    if (v != 0u && v != 1u && v != 0x3F800000u) atomicOr(&sflag[1], 1);
  }
  // W_eff[c][d] = (W0b - W0c)[d][c] + q[d]*W0d[d][c]  (d-major: coalesced W0 reads)
  for (int idx = tid; idx < 5120; idx += 256) {
    int d = idx / 80, c = idx - d*80;
    float we = (W0[(64+d)*80 + c] - W0[(128+d)*80 + c]) + sq[d]*W0[(192+d)*80 + c];
    unsigned short hi = f2bf_rne(we);
    sWhi[c*80 + d] = hi;
    sWlo[c*80 + d] = f2bf_rne(we - bf2f(hi));
  }
  // qc = b0 + q@(W0a+W0c): serial over d, coalesced across 80 threads (R4-proven)
  if (tid < 80) {
    float s = b0[tid];
    for (int d = 0; d < 64; ++d)
      s += sq[d] * (W0[d*80 + tid] + W0[(128+d)*80 + tid]);
    qc_g[b*80 + tid] = s;
  }
  // W1^T padded [48][96] hi/lo (block 0 only; 18KB, L2/L3-resident for k2)
  if (b == 0) {
    for (int idx = tid; idx < 48*96; idx += 256) {
      int c = idx / 96, k = idx - c*96;
      float w = (c < 40 && k < 80) ? W1[k*40 + c] : 0.f;
      unsigned short hi = f2bf_rne(w);
      w1t_hi[idx] = hi;
      w1t_lo[idx] = f2bf_rne(w - bf2f(hi));
    }
  }
  __syncthreads();
  // coalesced weff writeback
  for (int i2 = tid; i2 < 640; i2 += 256) {
    int c = i2 >> 3, dc = i2 & 7;
    uint4 vh = *reinterpret_cast<const uint4*>(&sWhi[c*80 + dc*8]);
    uint4 vl = *reinterpret_cast<const uint4*>(&sWlo[c*80 + dc*8]);
    *reinterpret_cast<uint4*>(&weff_hi[(size_t)b*5120 + c*64 + dc*8]) = vh;
    *reinterpret_cast<uint4*>(&weff_lo[(size_t)b*5120 + c*64 + dc*8]) = vl;
  }
  if (tid < 2) flagsP[b*2 + tid] = sflag[tid];
}

// ---------------- k1_main: h0 = k @ W_eff + qc via MFMA; prologue-free, vectorized stores ----------------
template<bool STORE>
__global__ __launch_bounds__(256) void k1_main(
    const float* __restrict__ key,
    const unsigned short* __restrict__ weff_hi, const unsigned short* __restrict__ weff_lo,
    const float* __restrict__ qc_g,
    unsigned short* __restrict__ h0, float* __restrict__ p0)
{
  __shared__ float sred[160];
  __shared__ __align__(16) unsigned short sT[4][16*80];   // wave-local store-transpose tiles
  int b = blockIdx.x, tid = threadIdx.x;
  for (int i = tid; i < 160; i += 256) sred[i] = 0.f;
  int wv = tid >> 6, l = tid & 63, lm = l & 15, lg = l >> 4;

  const unsigned short* wh = weff_hi + (size_t)b*5120;
  const unsigned short* wl = weff_lo + (size_t)b*5120;
  short8 bfr[5][2][2];
#pragma unroll
  for (int n = 0; n < 5; ++n)
#pragma unroll
    for (int ks = 0; ks < 2; ++ks) {
      int off = (n*16 + lm)*64 + ks*32 + lg*8;
      bfr[n][ks][0] = *reinterpret_cast<const short8*>(wh + off);
      bfr[n][ks][1] = *reinterpret_cast<const short8*>(wl + off);
    }
  float qcv[5];
#pragma unroll
  for (int n = 0; n < 5; ++n) qcv[n] = qc_g[b*80 + n*16 + lm];
  __syncthreads();

  float accS[5] = {0,0,0,0,0}, accQ[5] = {0,0,0,0,0};
  const float* keyb = key + (size_t)b*NT*ND;
  unsigned short* tb = &sT[wv][0];

  for (int mt = wv; mt < 13; mt += 4) {
    int t0 = mt*16;
    int trow = t0 + lm;
    int tld = trow < NT ? trow : NT-1;
    const float* arow = keyb + (size_t)tld*ND;
    short8 ahi[2], alo[2];
#pragma unroll
    for (int ks = 0; ks < 2; ++ks) {
      float4 av0 = *reinterpret_cast<const float4*>(arow + ks*32 + lg*8);
      float4 av1 = *reinterpret_cast<const float4*>(arow + ks*32 + lg*8 + 4);
      float xs[8] = {av0.x, av0.y, av0.z, av0.w, av1.x, av1.y, av1.z, av1.w};
#pragma unroll
      for (int j = 0; j < 8; ++j) {
        unsigned short hb = f2bf_rne(xs[j]);
        ahi[ks][j] = (short)hb;
        alo[ks][j] = (short)f2bf_rne(xs[j] - bf2f(hb));
      }
    }
    f32x4 acc[5];
#pragma unroll
    for (int n = 0; n < 5; ++n) {
      acc[n][0] = qcv[n]; acc[n][1] = qcv[n]; acc[n][2] = qcv[n]; acc[n][3] = qcv[n];
    }
#pragma unroll
    for (int n = 0; n < 5; ++n)
#pragma unroll
      for (int ks = 0; ks < 2; ++ks) {
        acc[n] = __builtin_amdgcn_mfma_f32_16x16x32_bf16(ahi[ks], bfr[n][ks][0], acc[n], 0, 0, 0);
        acc[n] = __builtin_amdgcn_mfma_f32_16x16x32_bf16(ahi[ks], bfr[n][ks][1], acc[n], 0, 0, 0);
        acc[n] = __builtin_amdgcn_mfma_f32_16x16x32_bf16(alo[ks], bfr[n][ks][0], acc[n], 0, 0, 0);
      }
    // C/D layout: col = lane&15, row = (lane>>4)*4 + reg
    if (STORE) {
      // drop fragments into wave-local LDS tile (same-wave ordering via lgkmcnt; no barrier)
#pragma unroll
      for (int n = 0; n < 5; ++n)
#pragma unroll
        for (int r = 0; r < 4; ++r)
          tb[(lg*4 + r)*80 + n*16 + lm] = f2bf_rne(acc[n][r]);
      // coalesced writeback: 160 uint4 per tile, 3 rounds
#pragma unroll
      for (int it = 0; it < 3; ++it) {
        int i = l + it*64;
        if (i < 160) {
          int row = i / 10, col = (i - row*10)*8;
          int gr = t0 + row;
          if (gr < NT) {
            uint4 v = *reinterpret_cast<const uint4*>(tb + row*80 + col);
            *reinterpret_cast<uint4*>(&h0[((size_t)b*NT + gr)*NH0 + col]) = v;
          }
        }
      }
    }
#pragma unroll
    for (int n = 0; n < 5; ++n)
#pragma unroll
      for (int r = 0; r < 4; ++r) {
        int row = t0 + lg*4 + r;
        if (row < NT) {
          float h = acc[n][r];
          accS[n] += h; accQ[n] += h*h;
        }
      }
  }
#pragma unroll
  for (int n = 0; n < 5; ++n) {
    accS[n] += __shfl_xor(accS[n], 16); accS[n] += __shfl_xor(accS[n], 32);
    accQ[n] += __shfl_xor(accQ[n], 16); accQ[n] += __shfl_xor(accQ[n], 32);
  }
  if (lg == 0) {
#pragma unroll
    for (int n = 0; n < 5; ++n) {
      atomicAdd(&sred[n*16 + lm], accS[n]);
      atomicAdd(&sred[80 + n*16 + lm], accQ[n]);
    }
  }
  __syncthreads();
  if (tid < 160) p0[(size_t)tid * PSTRIDE + b] = sred[tid];
}

// ---------------- k2_main: h1 = dice0(h0)@W1 + b1 via MFMA; vectorized stores ----------------
__global__ __launch_bounds__(256) void k2_main(
    const unsigned short* __restrict__ h0,
    const unsigned short* __restrict__ w1t_hi, const unsigned short* __restrict__ w1t_lo,
    const float* __restrict__ b1, const float* __restrict__ alpha0,
    const float* __restrict__ stats,
    unsigned short* __restrict__ h1, float* __restrict__ p1)
{
  __shared__ float sm0[96], si0[96], sa0[96];
  __shared__ float sb1[48];
  __shared__ float sred[80];
  __shared__ __align__(16) unsigned short sT[4][16*40];
  int tid = threadIdx.x;
  if (tid < 96) {
    sm0[tid] = (tid < 80) ? stats[tid] : 0.f;
    si0[tid] = (tid < 80) ? stats[80 + tid] : 0.f;
    sa0[tid] = (tid < 80) ? alpha0[tid] : 0.f;
  }
  if (tid >= 96 && tid < 144) sb1[tid-96] = (tid-96 < 40) ? b1[tid-96] : 0.f;
  if (tid >= 144 && tid < 224) sred[tid-144] = 0.f;
  __syncthreads();

  int wv = tid >> 6, l = tid & 63, lm = l & 15, lg = l >> 4;

  short8 bfr[3][3][2];
#pragma unroll
  for (int n = 0; n < 3; ++n)
#pragma unroll
    for (int ks = 0; ks < 3; ++ks) {
      int off = (n*16 + lm)*96 + ks*32 + lg*8;
      bfr[n][ks][0] = *reinterpret_cast<const short8*>(w1t_hi + off);
      bfr[n][ks][1] = *reinterpret_cast<const short8*>(w1t_lo + off);
    }
  float dm[3][8], di[3][8], da[3][8];
#pragma unroll
  for (int ks = 0; ks < 3; ++ks) {
    int k0 = ks*32 + lg*8;
#pragma unroll
    for (int j = 0; j < 8; ++j) {
      dm[ks][j] = sm0[k0+j]; di[ks][j] = si0[k0+j]; da[ks][j] = sa0[k0+j];
    }
  }

  float accS[3] = {0,0,0}, accQ[3] = {0,0,0};
  size_t row0 = (size_t)blockIdx.x*128 + wv*32;
  unsigned short* tb = &sT[wv][0];

  for (int mt = 0; mt < 2; ++mt) {
    size_t row = row0 + mt*16 + lm;
    const unsigned short* arow = h0 + row*NH0;
    short8 ya[3];
#pragma unroll
    for (int ks = 0; ks < 3; ++ks) {
      int el0 = ks*32 + lg*8;
      int elc = (el0 < 80) ? el0 : 0;
      uint4 xv = *reinterpret_cast<const uint4*>(arow + elc);
      unsigned uu[4] = {xv.x, xv.y, xv.z, xv.w};
#pragma unroll
      for (int j = 0; j < 8; ++j) {
        unsigned short hx = (j & 1) ? (unsigned short)(uu[j>>1] >> 16)
                                    : (unsigned short)(uu[j>>1] & 0xffffu);
        float x = bf2f(hx);
        float xn = (x - dm[ks][j]) * di[ks][j];
        float pp = 1.f / (1.f + __expf(-xn));
        float y = x * (da[ks][j] + pp*(1.f - da[ks][j]));
        ya[ks][j] = (short)f2bf_rne(y);
      }
    }
    f32x4 acc[3];
#pragma unroll
    for (int n = 0; n < 3; ++n) {
      float bv = sb1[n*16 + lm];
      acc[n][0] = bv; acc[n][1] = bv; acc[n][2] = bv; acc[n][3] = bv;
    }
#pragma unroll
    for (int n = 0; n < 3; ++n)
#pragma unroll
      for (int ks = 0; ks < 3; ++ks) {
        acc[n] = __builtin_amdgcn_mfma_f32_16x16x32_bf16(ya[ks], bfr[n][ks][0], acc[n], 0, 0, 0);
        acc[n] = __builtin_amdgcn_mfma_f32_16x16x32_bf16(ya[ks], bfr[n][ks][1], acc[n], 0, 0, 0);
      }
    // stage to wave-local LDS tile, then coalesced uint4 writeback
#pragma unroll
    for (int n = 0; n < 3; ++n) {
      int c = n*16 + lm;
      if (c < 40) {
#pragma unroll
        for (int r = 0; r < 4; ++r) {
          float h = acc[n][r];
          tb[(lg*4 + r)*40 + c] = f2bf_rne(h);
          accS[n] += h; accQ[n] += h*h;
        }
      }
    }
    // 80 uint4 per tile: 2 rounds
#pragma unroll
    for (int it = 0; it < 2; ++it) {
      int i = l + it*64;
      if (i < 80) {
        int r = i / 5, col = (i - r*5)*8;
        uint4 v = *reinterpret_cast<const uint4*>(tb + r*40 + col);
        *reinterpret_cast<uint4*>(&h1[(row0 + mt*16 + r)*NH1 + col]) = v;
      }
    }
  }
#pragma unroll
  for (int n = 0; n < 3; ++n) {
    accS[n] += __shfl_xor(accS[n], 16); accS[n] += __shfl_xor(accS[n], 32);
    accQ[n] += __shfl_xor(accQ[n], 16); accQ[n] += __shfl_xor(accQ[n], 32);
  }
  if (lg == 0) {
#pragma unroll
    for (int n = 0; n < 3; ++n) {
      int c = n*16 + lm;
      if (c < 40) { atomicAdd(&sred[c], accS[n]); atomicAdd(&sred[40 + c], accQ[n]); }
    }
  }
  __syncthreads();
  if (tid < 80) p1[(size_t)tid * PSTRIDE + blockIdx.x] = sred[tid];
}

// ---------------- partial -> mean/inv reduction (+ optional mask-flag fold) ----------------
__global__ __launch_bounds__(256) void reduce_stats_kernel(
    const float* __restrict__ p, int stride, int nblk, int nch,
    float* __restrict__ mean_out, float* __restrict__ inv_out,
    const int* __restrict__ flagsP, int* __restrict__ flags_out, int nflag)
{
  int c = blockIdx.x, tid = threadIdx.x;
  float s = 0.f, q = 0.f;
  for (int j = tid; j < nblk; j += 256) {
    s += p[(size_t)c*stride + j];
    q += p[(size_t)(nch + c)*stride + j];
  }
#pragma unroll
  for (int off = 32; off > 0; off >>= 1) { s += __shfl_xor(s, off); q += __shfl_xor(q, off); }
  __shared__ float ss[4], sq[4];
  __shared__ int sfo[2];
  if ((tid & 63) == 0) { ss[tid >> 6] = s; sq[tid >> 6] = q; }
  if (tid < 2) sfo[tid] = 0;
  __syncthreads();
  if (tid == 0) {
    float S = ss[0]+ss[1]+ss[2]+ss[3], Q = sq[0]+sq[1]+sq[2]+sq[3];
    float invN = 1.f / (float)NROWS;
    float mean = S * invN;
    float var  = Q * invN - mean*mean;
    mean_out[c] = mean;
    inv_out[c]  = rsqrtf(var + 1e-9f);
  }
  if (flagsP != nullptr && c == 0) {
    int f0 = 0, f1 = 0;
    for (int i = tid; i < nflag; i += 256) { f0 |= flagsP[2*i]; f1 |= flagsP[2*i + 1]; }
    if (f0) atomicOr(&sfo[0], 1);
    if (f1) atomicOr(&sfo[1], 1);
    __syncthreads();
    if (tid < 2) flags_out[tid] = sfo[tid];
  }
}

// ---------------- k3: dice1, scores, softmax, attn@key (key staged in LDS) ----------------
__device__ __forceinline__ bool read_mask(const void* mask, int mode, size_t mi) {
  if (mode == 0) return ((const int*)mask)[mi] != 0;
  if (mode == 1) return ((const unsigned char*)mask)[mi] != 0;
  return ((const float*)mask)[mi] != 0.f;
}

__global__ __launch_bounds__(256) void k3_kernel(
    const unsigned short* __restrict__ h1, const float* __restrict__ Wout,
    const float* __restrict__ bout, const float* __restrict__ alpha1,
    const void* __restrict__ mask, const float* __restrict__ key,
    const float* __restrict__ stats, const int* __restrict__ flags,
    float* __restrict__ out)
{
  __shared__ float sk[NT*ND];                 // 51,200 B key block
  __shared__ float sWo[40], sm1[40], si1[40], sa1[40];
  __shared__ float sp[256], sredm[4], ssum[4], sout[256];
  int b = blockIdx.x, tid = threadIdx.x;

  // bulk-parallel stage of the key block (3200 independent float4 loads)
  const float4* kb4 = (const float4*)(key + (size_t)b*NT*ND);
  float4* sk4 = (float4*)sk;
  for (int i = tid; i < NT*ND/4; i += 256) sk4[i] = kb4[i];

  if (tid < 40) {
    sWo[tid] = Wout[tid];
    sm1[tid] = stats[160 + tid]; si1[tid] = stats[200 + tid]; sa1[tid] = alpha1[tid];
  }
  __syncthreads();
  int mode = (flags[0] == 0) ? 0 : ((flags[1] == 0) ? 2 : 1);
  float sc = -FLT_MAX;
  if (tid < NT) {
    const uint4* xr = (const uint4*)(h1 + ((size_t)b*NT + tid)*NH1);
    float s = bout[0];
#pragma unroll
    for (int cq = 0; cq < 5; ++cq) {
      uint4 xv = xr[cq];
      unsigned uu[4] = {xv.x, xv.y, xv.z, xv.w};
#pragma unroll
      for (int u = 0; u < 8; ++u) {
        int c = cq*8 + u;
        unsigned short hx = (u & 1) ? (unsigned short)(uu[u>>1] >> 16)
                                    : (unsigned short)(uu[u>>1] & 0xffffu);
        float x = bf2f(hx);
        float xn = (x - sm1[c]) * si1[c];
        float p = 1.f / (1.f + __expf(-xn));
        float y = x * (sa1[c] + p*(1.f - sa1[c]));
        s = fmaf(y, sWo[c], s);
      }
    }
    if (read_mask(mask, mode, (size_t)b*NT + tid)) sc = s;
  }
  // softmax
  float m = sc;
#pragma unroll
  for (int off = 32; off > 0; off >>= 1) m = fmaxf(m, __shfl_xor(m, off));
  if ((tid & 63) == 0) sredm[tid >> 6] = m;
  __syncthreads();
  float mm = fmaxf(fmaxf(sredm[0], sredm[1]), fmaxf(sredm[2], sredm[3]));
  float e = (sc > -FLT_MAX) ? __expf(sc - mm) : 0.f;
  float sv = e;
#pragma unroll
  for (int off = 32; off > 0; off >>= 1) sv += __shfl_xor(sv, off);
  if ((tid & 63) == 0) ssum[tid >> 6] = sv;
  __syncthreads();
  float inv = 1.f / (ssum[0] + ssum[1] + ssum[2] + ssum[3]);
  sp[tid] = e * inv;
  __syncthreads();
  // PV from LDS: 4-way split accumulator, conflict-free (2 lanes/bank)
  int wid = tid >> 6, lane = tid & 63;
  float a0 = 0.f, a1 = 0.f, a2 = 0.f, a3 = 0.f;
  int t = wid;
#pragma unroll 4
  for (; t + 12 < NT; t += 16) {
    a0 = fmaf(sp[t],      sk[t*ND + lane],      a0);
    a1 = fmaf(sp[t+4],    sk[(t+4)*ND + lane],  a1);
    a2 = fmaf(sp[t+8],    sk[(t+8)*ND + lane],  a2);
    a3 = fmaf(sp[t+12],   sk[(t+12)*ND + lane], a3);
  }
  for (; t < NT; t += 4) a0 = fmaf(sp[t], sk[t*ND + lane], a0);
  sout[tid] = (a0 + a1) + (a2 + a3);
  __syncthreads();
  if (tid < 64) out[b*64 + tid] = sout[tid] + sout[64+tid] + sout[128+tid] + sout[192+tid];
}

// ================= fallback kernels (small ws) =================

__global__ void detect_mask_kernel(const unsigned* __restrict__ m, int* __restrict__ flags) {
  int i = blockIdx.x * 256 + threadIdx.x;
  if (i < NROWS / 4) {
    unsigned v = m[i];
    if (v > 1u) atomicOr(&flags[0], 1);
    if (v != 0u && v != 1u && v != 0x3F800000u) atomicOr(&flags[1], 1);
  }
}

__device__ __forceinline__ void softmax_and_out(
    int b, int tid, float sc, float* sp, float* sredm, float* ssum, float* sout,
    const float* __restrict__ key, float* __restrict__ out)
{
  float m = sc;
#pragma unroll
  for (int off = 32; off > 0; off >>= 1) m = fmaxf(m, __shfl_xor(m, off));
  if ((tid & 63) == 0) sredm[tid >> 6] = m;
  __syncthreads();
  float mm = fmaxf(fmaxf(sredm[0], sredm[1]), fmaxf(sredm[2], sredm[3]));
  float e = (sc > -FLT_MAX) ? __expf(sc - mm) : 0.f;
  float sv = e;
#pragma unroll
  for (int off = 32; off > 0; off >>= 1) sv += __shfl_xor(sv, off);
  if ((tid & 63) == 0) ssum[tid >> 6] = sv;
  __syncthreads();
  float inv = 1.f / (ssum[0] + ssum[1] + ssum[2] + ssum[3]);
  sp[tid] = e * inv;
  __syncthreads();
  int wid = tid >> 6, lane = tid & 63;
  const float* keyb = key + (size_t)b*NT*ND;
  float acc = 0.f;
  for (int t = wid; t < NT; t += 4) acc = fmaf(sp[t], keyb[t*ND + lane], acc);
  sout[tid] = acc;
  __syncthreads();
  if (tid < 64) out[b*64 + tid] = sout[tid] + sout[64+tid] + sout[128+tid] + sout[192+tid];
}

__global__ __launch_bounds__(256) void k1_old(
    const float* __restrict__ query, const float* __restrict__ key,
    const float* __restrict__ W0, const float* __restrict__ b0,
    float* __restrict__ p0)
{
  __shared__ __align__(16) unsigned short sWhi[80*72];
  __shared__ __align__(16) unsigned short sWlo[80*72];
  __shared__ float sq[64];
  __shared__ float sqc[80];
  __shared__ float sred[160];
  int b = blockIdx.x, tid = threadIdx.x;

  if (tid < 64) sq[tid] = query[b*64 + tid];
  for (int i = tid; i < 160; i += 256) sred[i] = 0.f;
  __syncthreads();
  for (int idx = tid; idx < 64*80; idx += 256) {
    int d = idx / 80, c = idx - d*80;
    float we = (W0[(64+d)*80 + c] - W0[(128+d)*80 + c]) + sq[d]*W0[(192+d)*80 + c];
    unsigned short hi = f2bf_rne(we);
    sWhi[c*72 + d] = hi;
    sWlo[c*72 + d] = f2bf_rne(we - bf2f(hi));
  }
  if (tid < 80) {
    float s = b0[tid];
    for (int d = 0; d < 64; ++d)
      s += sq[d] * (W0[d*80 + tid] + W0[(128+d)*80 + tid]);
    sqc[tid] = s;
  }
  __syncthreads();

  int wv = tid >> 6, l = tid & 63;
  int lm = l & 15, lg = l >> 4;
  short8 bfr[5][2][2];
#pragma unroll
  for (int n = 0; n < 5; ++n)
#pragma unroll
    for (int ks = 0; ks < 2; ++ks) {
      int off = (n*16 + lm)*72 + ks*32 + lg*8;
      bfr[n][ks][0] = *reinterpret_cast<const short8*>(&sWhi[off]);
      bfr[n][ks][1] = *reinterpret_cast<const short8*>(&sWlo[off]);
    }
  float accS[5] = {0,0,0,0,0}, accQ[5] = {0,0,0,0,0};
  const float* keyb = key + (size_t)b*NT*ND;

  for (int mt = wv; mt < 13; mt += 4) {
    int t0 = mt*16;
    int trow = t0 + lm;
    int tld = trow < NT ? trow : NT-1;
    const float* arow = keyb + (size_t)tld*ND;
    short8 ahi[2], alo[2];
#pragma unroll
    for (int ks = 0; ks < 2; ++ks) {
      float4 av0 = *reinterpret_cast<const float4*>(arow + ks*32 + lg*8);
      float4 av1 = *reinterpret_cast<const float4*>(arow + ks*32 + lg*8 + 4);
      float xs[8] = {av0.x, av0.y, av0.z, av0.w, av1.x, av1.y, av1.z, av1.w};
#pragma unroll
      for (int j = 0; j < 8; ++j) {
        unsigned short hb = f2bf_rne(xs[j]);
        ahi[ks][j] = (short)hb;
        alo[ks][j] = (short)f2bf_rne(xs[j] - bf2f(hb));
      }
    }
    f32x4 acc[5];
#pragma unroll
    for (int n = 0; n < 5; ++n) {
      float qcv = sqc[n*16 + lm];
      acc[n][0] = qcv; acc[n][1] = qcv; acc[n][2] = qcv; acc[n][3] = qcv;
    }
#pragma unroll
    for (int n = 0; n < 5; ++n)
#pragma unroll
      for (int ks = 0; ks < 2; ++ks) {
        acc[n] = __builtin_amdgcn_mfma_f32_16x16x32_bf16(ahi[ks], bfr[n][ks][0], acc[n], 0, 0, 0);
        acc[n] = __builtin_amdgcn_mfma_f32_16x16x32_bf16(ahi[ks], bfr[n][ks][1], acc[n], 0, 0, 0);
        acc[n] = __builtin_amdgcn_mfma_f32_16x16x32_bf16(alo[ks], bfr[n][ks][0], acc[n], 0, 0, 0);
      }
#pragma unroll
    for (int n = 0; n < 5; ++n)
#pragma unroll
      for (int r = 0; r < 4; ++r) {
        int row = t0 + lg*4 + r;
        if (row < NT) { float h = acc[n][r]; accS[n] += h; accQ[n] += h*h; }
      }
  }
#pragma unroll
  for (int n = 0; n < 5; ++n) {
    accS[n] += __shfl_xor(accS[n], 16); accS[n] += __shfl_xor(accS[n], 32);
    accQ[n] += __shfl_xor(accQ[n], 16); accQ[n] += __shfl_xor(accQ[n], 32);
  }
  if (lg == 0) {
#pragma unroll
    for (int n = 0; n < 5; ++n) {
      atomicAdd(&sred[n*16 + lm], accS[n]);
      atomicAdd(&sred[80 + n*16 + lm], accQ[n]);
    }
  }
  __syncthreads();
  if (tid < 160) p0[(size_t)tid * PSTRIDE + b] = sred[tid];
}

template<bool STOREH1>
__global__ __launch_bounds__(256) void k2_rec_kernel(
    const float* __restrict__ query, const float* __restrict__ key,
    const float* __restrict__ W0, const float* __restrict__ b0,
    const float* __restrict__ W1, const float* __restrict__ b1,
    const float* __restrict__ alpha0,
    unsigned short* __restrict__ h1, const float* __restrict__ stats,
    float* __restrict__ p1)
{
  __shared__ float sWb[64*80], sWd[64*80], sW1[80*40];
  __shared__ float sq[64], sqc[80], sb1[40];
  __shared__ float sm0[80], si0[80], sa0[80];
  __shared__ float swp[4*80];
  int b = blockIdx.x, tid = threadIdx.x;
  for (int idx = tid; idx < 64*80; idx += 256) {
    int d = idx / 80, c = idx - d*80;
    sWb[idx] = W0[(64+d)*80 + c] - W0[(128+d)*80 + c];
    sWd[idx] = W0[(192+d)*80 + c];
  }
  for (int idx = tid; idx < 3200; idx += 256) sW1[idx] = W1[idx];
  if (tid < 64) sq[tid] = query[b*64 + tid];
  if (tid < 40) sb1[tid] = b1[tid];
  if (tid >= 64 && tid < 144) {
    int c = tid - 64;
    sm0[c] = stats[c]; si0[c] = stats[80 + c]; sa0[c] = alpha0[c];
  }
  __syncthreads();
  if (tid < 80) {
    float s = b0[tid];
    for (int d = 0; d < 64; ++d)
      s += sq[d] * (W0[d*80 + tid] + W0[(128+d)*80 + tid]);
    sqc[tid] = s;
  }
  __syncthreads();
  int t = tid;
  bool active = t < NT;
  float h0r[80];
#pragma unroll
  for (int c = 0; c < 80; ++c) h0r[c] = sqc[c];
  const float* krow = key + ((size_t)b*NT + (active ? t : 0))*ND;
  for (int dq = 0; dq < 16; ++dq) {
    float4 kv = ((const float4*)krow)[dq];
#pragma unroll
    for (int u = 0; u < 4; ++u) {
      int d = dq*4 + u;
      float kd = (&kv.x)[u];
      float qk = sq[d] * kd;
#pragma unroll
      for (int c = 0; c < 80; ++c)
        h0r[c] = fmaf(kd, sWb[d*80 + c], fmaf(qk, sWd[d*80 + c], h0r[c]));
    }
  }
  float h1r[40];
#pragma unroll
  for (int c = 0; c < 40; ++c) h1r[c] = sb1[c];
#pragma unroll
  for (int d = 0; d < 80; ++d) {
    float x = h0r[d];
    float xn = (x - sm0[d]) * si0[d];
    float p = 1.f / (1.f + __expf(-xn));
    float y = x * (sa0[d] + p*(1.f - sa0[d]));
#pragma unroll
    for (int c = 0; c < 40; ++c) h1r[c] = fmaf(y, sW1[d*40 + c], h1r[c]);
  }
  if (STOREH1 && active) {
    uint4* orow = (uint4*)(h1 + ((size_t)b*NT + t)*NH1);
#pragma unroll
    for (int cq = 0; cq < 5; ++cq) {
      uint4 o;
      o.x = (unsigned)f2bf_rne(h1r[cq*8+0]) | ((unsigned)f2bf_rne(h1r[cq*8+1]) << 16);
      o.y = (unsigned)f2bf_rne(h1r[cq*8+2]) | ((unsigned)f2bf_rne(h1r[cq*8+3]) << 16);
      o.z = (unsigned)f2bf_rne(h1r[cq*8+4]) | ((unsigned)f2bf_rne(h1r[cq*8+5]) << 16);
      o.w = (unsigned)f2bf_rne(h1r[cq*8+6]) | ((unsigned)f2bf_rne(h1r[cq*8+7]) << 16);
      orow[cq] = o;
    }
  }
  int lane = tid & 63, wid = tid >> 6;
#pragma unroll
  for (int c = 0; c < 40; ++c) {
    float v = active ? h1r[c] : 0.f;
    float s = v, q = v*v;
#pragma unroll
    for (int off = 32; off > 0; off >>= 1) { s += __shfl_xor(s, off); q += __shfl_xor(q, off); }
    if (lane == 0) { swp[wid*80 + c] = s; swp[wid*80 + 40 + c] = q; }
  }
  __syncthreads();
  if (tid < 80) {
    float v = swp[tid] + swp[80+tid] + swp[160+tid] + swp[240+tid];
    p1[(size_t)tid * PSTRIDE + b] = v;
  }
}

__global__ __launch_bounds__(256) void k3_rec_kernel(
    const float* __restrict__ query, const float* __restrict__ key,
    const float* __restrict__ W0, const float* __restrict__ b0,
    const float* __restrict__ W1, const float* __restrict__ b1,
    const float* __restrict__ alpha0, const float* __restrict__ Wout,
    const float* __restrict__ bout, const float* __restrict__ alpha1,
    const void* __restrict__ mask,
    const float* __restrict__ stats, const int* __restrict__ flags,
    float* __restrict__ out)
{
  __shared__ float sWb[64*80], sWd[64*80], sW1[80*40];
  __shared__ float sq[64], sqc[80], sb1[40];
  __shared__ float sm0[80], si0[80], sa0[80];
  __shared__ float sWo[40], sm1[40], si1[40], sa1[40];
  __shared__ float sp[256], sredm[4], ssum[4], sout[256];
  int b = blockIdx.x, tid = threadIdx.x;
  for (int idx = tid; idx < 64*80; idx += 256) {
    int d = idx / 80, c = idx - d*80;
    sWb[idx] = W0[(64+d)*80 + c] - W0[(128+d)*80 + c];
    sWd[idx] = W0[(192+d)*80 + c];
  }
  for (int idx = tid; idx < 3200; idx += 256) sW1[idx] = W1[idx];
  if (tid < 64) sq[tid] = query[b*64 + tid];
  if (tid < 40) sb1[tid] = b1[tid];
  if (tid >= 64 && tid < 144) {
    int c = tid - 64;
    sm0[c] = stats[c]; si0[c] = stats[80 + c]; sa0[c] = alpha0[c];
  }
  if (tid >= 144 && tid < 184) {
    int c = tid - 144;
    sm1[c] = stats[160 + c]; si1[c] = stats[200 + c]; sa1[c] = alpha1[c];
    sWo[c] = Wout[c];
  }
  __syncthreads();
  if (tid < 80) {
    float s = b0[tid];
    for (int d = 0; d < 64; ++d)
      s += sq[d] * (W0[d*80 + tid] + W0[(128+d)*80 + tid]);
    sqc[tid] = s;
  }
  __syncthreads();
  int t = tid;
  bool active = t < NT;
  int mode = (flags[0] == 0) ? 0 : ((flags[1] == 0) ? 2 : 1);
  float sc = -FLT_MAX;
  {
    float h0r[80];
#pragma unroll
    for (int c = 0; c < 80; ++c) h0r[c] = sqc[c];
    const float* krow = key + ((size_t)b*NT + (active ? t : 0))*ND;
    for (int dq = 0; dq < 16; ++dq) {
      float4 kv = ((const float4*)krow)[dq];
#pragma unroll
      for (int u = 0; u < 4; ++u) {
        int d = dq*4 + u;
        float kd = (&kv.x)[u];
        float qk = sq[d] * kd;
#pragma unroll
        for (int c = 0; c < 80; ++c)
          h0r[c] = fmaf(kd, sWb[d*80 + c], fmaf(qk, sWd[d*80 + c], h0r[c]));
      }
    }
    float h1r[40];
#pragma unroll
    for (int c = 0; c < 40; ++c) h1r[c] = sb1[c];
#pragma unroll
    for (int d = 0; d < 80; ++d) {
      float x = h0r[d];
      float xn = (x - sm0[d]) * si0[d];
      float p = 1.f / (1.f + __expf(-xn));
      float y = x * (sa0[d] + p*(1.f - sa0[d]));
#pragma unroll
      for (int c = 0; c < 40; ++c) h1r[c] = fmaf(y, sW1[d*40 + c], h1r[c]);
    }
    float s = bout[0];
#pragma unroll
    for (int c = 0; c < 40; ++c) {
      float x = h1r[c];
      float xn = (x - sm1[c]) * si1[c];
      float p = 1.f / (1.f + __expf(-xn));
      float y = x * (sa1[c] + p*(1.f - sa1[c]));
      s = fmaf(y, sWo[c], s);
    }
    if (active && read_mask(mask, mode, (size_t)b*NT + t)) sc = s;
  }
  softmax_and_out(b, tid, sc, sp, sredm, ssum, sout, key, out);
}

// ================= launch =================

extern "C" void kernel_launch(void* const* d_in, const int* in_sizes, int n_in,
                              void* d_out, int out_size, void* d_ws, size_t ws_size,
                              hipStream_t stream) {
  const float* query  = (const float*)d_in[0];
  const float* key    = (const float*)d_in[1];
  const void*  mask   = d_in[2];
  const float* W0     = (const float*)d_in[3];
  const float* b0     = (const float*)d_in[4];
  const float* alpha0 = (const float*)d_in[5];
  const float* W1     = (const float*)d_in[6];
  const float* b1     = (const float*)d_in[7];
  const float* alpha1 = (const float*)d_in[8];
  const float* Wout   = (const float*)d_in[9];
  const float* bout   = (const float*)d_in[10];
  float* out = (float*)d_out;

  char* wsb = (char*)d_ws;
  float* stats = (float*)wsb;              // 960 B
  int* flags = (int*)(wsb + 960);          // 2 ints

  const size_t off_p0     = 1024;
  const size_t off_p1     = 1311744;
  const size_t off_flagsP = 1967104;
  const size_t off_qc     = 1975296;
  const size_t off_w1h    = 2302976;
  const size_t off_w1l    = 2312192;
  const size_t off_whi    = 2321408;
  const size_t off_wlo    = 12807168;
  const size_t off_h0     = 23292928;
  const size_t off_h1     = 56060928;
  const size_t END_FULL   = 72444928;
  const size_t END_MID    = off_h0 + 16384000;

  float* p0 = (float*)(wsb + off_p0);
  float* p1 = (float*)(wsb + off_p1);
  int* flagsP = (int*)(wsb + off_flagsP);
  float* qc_g = (float*)(wsb + off_qc);
  unsigned short* w1t_hi = (unsigned short*)(wsb + off_w1h);
  unsigned short* w1t_lo = (unsigned short*)(wsb + off_w1l);
  unsigned short* weff_hi = (unsigned short*)(wsb + off_whi);
  unsigned short* weff_lo = (unsigned short*)(wsb + off_wlo);

  if (ws_size >= END_FULL) {
    unsigned short* h0 = (unsigned short*)(wsb + off_h0);
    unsigned short* h1 = (unsigned short*)(wsb + off_h1);
    prep_kernel<<<NB, 256, 0, stream>>>(query, W0, b0, W1, (const unsigned*)mask,
                                        weff_hi, weff_lo, qc_g, w1t_hi, w1t_lo, flagsP);
    k1_main<true><<<NB, 256, 0, stream>>>(key, weff_hi, weff_lo, qc_g, h0, p0);
    reduce_stats_kernel<<<80, 256, 0, stream>>>(p0, PSTRIDE, NB, 80, stats, stats + 80,
                                                flagsP, flags, NB);
    k2_main<<<NROWS/128, 256, 0, stream>>>(h0, w1t_hi, w1t_lo, b1, alpha0, stats, h1, p1);
    reduce_stats_kernel<<<40, 256, 0, stream>>>(p1, PSTRIDE, NROWS/128, 40, stats + 160, stats + 200,
                                                nullptr, nullptr, 0);
    k3_kernel<<<NB, 256, 0, stream>>>(h1, Wout, bout, alpha1, mask, key, stats, flags, out);
  } else if (ws_size >= END_MID) {
    unsigned short* h1 = (unsigned short*)(wsb + off_h0);
    prep_kernel<<<NB, 256, 0, stream>>>(query, W0, b0, W1, (const unsigned*)mask,
                                        weff_hi, weff_lo, qc_g, w1t_hi, w1t_lo, flagsP);
    k1_main<false><<<NB, 256, 0, stream>>>(key, weff_hi, weff_lo, qc_g, nullptr, p0);
    reduce_stats_kernel<<<80, 256, 0, stream>>>(p0, PSTRIDE, NB, 80, stats, stats + 80,
                                                flagsP, flags, NB);
    k2_rec_kernel<true><<<NB, 256, 0, stream>>>(query, key, W0, b0, W1, b1, alpha0, h1, stats, p1);
    reduce_stats_kernel<<<40, 256, 0, stream>>>(p1, PSTRIDE, NB, 40, stats + 160, stats + 200,
                                                nullptr, nullptr, 0);
    k3_kernel<<<NB, 256, 0, stream>>>(h1, Wout, bout, alpha1, mask, key, stats, flags, out);
  } else {
    hipMemsetAsync(d_ws, 0, 1024, stream);
    detect_mask_kernel<<<200, 256, 0, stream>>>((const unsigned*)mask, flags);
    k1_old<<<NB, 256, 0, stream>>>(query, key, W0, b0, p0);
    reduce_stats_kernel<<<80, 256, 0, stream>>>(p0, PSTRIDE, NB, 80, stats, stats + 80,
                                                nullptr, nullptr, 0);
    k2_rec_kernel<false><<<NB, 256, 0, stream>>>(query, key, W0, b0, W1, b1, alpha0, nullptr, stats, p1);
    reduce_stats_kernel<<<40, 256, 0, stream>>>(p1, PSTRIDE, NB, 40, stats + 160, stats + 200,
                                                nullptr, nullptr, 0);
    k3_rec_kernel<<<NB, 256, 0, stream>>>(query, key, W0, b0, W1, b1, alpha0, Wout, bout, alpha1,
                                          mask, stats, flags, out);
  }
}